// Round 1
// 500.270 us; speedup vs baseline: 1.0396x; 1.0396x over previous
//
#include <hip/hip_runtime.h>
#include <hip/hip_bf16.h>
#include <stdint.h>

#define B_DIM 8192
#define IN_DIMC 1024
#define HIDC 1024
#define K_DIM 1024
#define ODE_STEPS 6

typedef float f32x4 __attribute__((ext_vector_type(4)));
typedef short bf16x8 __attribute__((ext_vector_type(8)));
typedef unsigned short u16x8 __attribute__((ext_vector_type(8)));

__device__ __forceinline__ float bf2f(unsigned short u) {
    union { unsigned int u; float f; } c; c.u = ((unsigned int)u) << 16; return c.f;
}
__device__ __forceinline__ unsigned short f2bf(float f) {
    union { float f; unsigned int u; } c; c.f = f;
    unsigned int u = c.u;
    return (unsigned short)((u + 0x7fffu + ((u >> 16) & 1u)) >> 16);
}
__device__ __forceinline__ float fast_tanh(float x) {
    float e = __expf(2.0f * x);
    return 1.0f - 2.0f / (e + 1.0f);
}

// ---------------- convert all f32 inputs to bf16 in workspace ----------------
constexpr size_t XN    = (size_t)B_DIM * IN_DIMC;
constexpr size_t HN    = (size_t)B_DIM * HIDC;
constexpr size_t WINN  = (size_t)HIDC * IN_DIMC;
constexpr size_t WRECN = (size_t)HIDC * HIDC;
constexpr size_t WGN   = (size_t)HIDC * (IN_DIMC + HIDC);
constexpr size_t TOTQ  = (XN + HN + WINN + WRECN + WGN) / 4;

__global__ __launch_bounds__(256) void convert_all(
    const float* __restrict__ x, const float* __restrict__ h,
    const float* __restrict__ win, const float* __restrict__ wrec,
    const float* __restrict__ wgate,
    unsigned short* __restrict__ x_bf, unsigned short* __restrict__ h_bf,
    unsigned short* __restrict__ win_bf, unsigned short* __restrict__ wrec_bf,
    unsigned short* __restrict__ wgx_bf, unsigned short* __restrict__ wgh_bf)
{
    size_t q = (size_t)blockIdx.x * 256 + threadIdx.x;
    if (q >= TOTQ) return;
    size_t e = q * 4;
    const float* src; unsigned short* dst; size_t si, di;
    if (e < XN)                          { src = x;    si = e;                       dst = x_bf;    di = si; }
    else if (e < XN + HN)                { src = h;    si = e - XN;                  dst = h_bf;    di = si; }
    else if (e < XN + HN + WINN)         { src = win;  si = e - XN - HN;             dst = win_bf;  di = si; }
    else if (e < XN + HN + WINN + WRECN) { src = wrec; si = e - XN - HN - WINN;      dst = wrec_bf; di = si; }
    else {
        size_t i = e - XN - HN - WINN - WRECN;
        size_t row = i >> 11, col = i & 2047;
        src = wgate; si = i;
        if (col < 1024) { dst = wgx_bf; di = row * 1024 + col; }
        else            { dst = wgh_bf; di = row * 1024 + (col - 1024); }
    }
    float4 v = *(const float4*)(src + si);
    ushort4 o;
    o.x = f2bf(v.x); o.y = f2bf(v.y); o.z = f2bf(v.z); o.w = f2bf(v.w);
    *(ushort4*)(dst + di) = o;
}

// ---- fused dual-GEMM, 2-phase pipelined core (BM=128 BN=128 BK=32, 2 blk/CU) ----
// Schedule = catalog "minimum 2-phase": per K-iter issue next-tile
// global_load_lds into buf^1 FIRST, then ds_read+MFMA on buf, then one
// __syncthreads() (its vmcnt(0) drain lands after the MFMA cluster).
// Grid = 512 = 2 blocks/CU exactly -> all blocks co-resident, no tail.
// Epilogue state (GX/ID bf16, carried h f32) in accumulator-native layout:
// slot = ((bid*4 + wave)*16 + mi*4+ni)*64 + lane  (16B/lane full-line access).
constexpr int BM = 128, BN = 128, BK = 32;
constexpr int NT = HIDC / BN;          // 8
constexpr int GRID = (B_DIM / BM) * NT; // 512

__device__ __forceinline__ void gload_lds16(const void* g, void* l) {
    __builtin_amdgcn_global_load_lds(
        (const __attribute__((address_space(1))) void*)g,
        (__attribute__((address_space(3))) void*)l, 16, 0, 0);
}

template<bool STEP>
__global__ __launch_bounds__(256, 2) void ltc_gemm(
    const unsigned short* __restrict__ A,
    const unsigned short* __restrict__ B1,
    const unsigned short* __restrict__ B2,
    const unsigned short* __restrict__ GXID,   // native layout, 8 bf16/slot
    const float* __restrict__ h_init,          // row-major f32 (step 0 only)
    float* __restrict__ h_nat,                 // native f32 state, in-place
    const float* __restrict__ log_tau,
    float* __restrict__ h_out,                 // final step: d_out half 0
    float* __restrict__ h_out2,                // final step: d_out half 1
    unsigned short* __restrict__ hbf_out,      // row-major bf16 (next A)
    const float* __restrict__ bias1, const float* __restrict__ bias2,
    unsigned short* __restrict__ GXID_out)     // pre-kernel output
{
    __shared__ __attribute__((aligned(16))) unsigned short lA [2][BM * BK]; // 16 KB
    __shared__ __attribute__((aligned(16))) unsigned short lB1[2][BN * BK]; // 16 KB
    __shared__ __attribute__((aligned(16))) unsigned short lB2[2][BN * BK]; // 16 KB

    const int tid = threadIdx.x;
    const int w = tid >> 6, l = tid & 63;
    // bijective XCD swizzle (GRID % 8 == 0): 8 n-blocks of one m-panel share an XCD L2
    const int bid = (blockIdx.x & 7) * (GRID / 8) + (blockIdx.x >> 3);
    const int mt = bid / NT, nt = bid % NT;
    const int m0 = mt * BM, n0 = nt * BN;
    const int wm = (w >> 1) * 64, wn = (w & 1) * 64;
    const int lrow = l >> 2, lcol = (l & 3) * 8;   // staging: 16 rows x 64B per wave-round
    const int lm = l & 15, lq = l >> 4;

    f32x4 acc1[4][4], acc2[4][4];
    f32x4 z4 = {0.f, 0.f, 0.f, 0.f};
    #pragma unroll
    for (int i = 0; i < 4; i++)
        #pragma unroll
        for (int j = 0; j < 4; j++) { acc1[i][j] = z4; acc2[i][j] = z4; }

    // staging bases: wave w stages rows [w*32, w*32+32) of each of the 3 tiles
    const int srow = w * 32 + lrow;
    const unsigned short* gA  = A  + (size_t)(m0 + srow) * K_DIM + lcol;
    const unsigned short* gB1 = B1 + (size_t)(n0 + srow) * K_DIM + lcol;
    const unsigned short* gB2 = B2 + (size_t)(n0 + srow) * K_DIM + lcol;
    const int lo = (w * 32) * BK;                  // wave-uniform LDS elem offset

    auto STAGE = [&](int buf, int k0) {
        gload_lds16(gA  + k0,               &lA [buf][lo]);
        gload_lds16(gA  + 16 * K_DIM + k0,  &lA [buf][lo + 16 * BK]);
        gload_lds16(gB1 + k0,               &lB1[buf][lo]);
        gload_lds16(gB1 + 16 * K_DIM + k0,  &lB1[buf][lo + 16 * BK]);
        gload_lds16(gB2 + k0,               &lB2[buf][lo]);
        gload_lds16(gB2 + 16 * K_DIM + k0,  &lB2[buf][lo + 16 * BK]);
    };

    STAGE(0, 0);
    __syncthreads();
    int cur = 0;
    for (int k0 = 0; k0 < K_DIM; k0 += BK) {
        if (k0 + BK < K_DIM) STAGE(cur ^ 1, k0 + BK);   // prefetch overlaps compute

        bf16x8 af[4], f1[4], f2[4];
        #pragma unroll
        for (int mi = 0; mi < 4; mi++)
            af[mi] = *(const bf16x8*)&lA[cur][(wm + mi * 16 + lm) * BK + lq * 8];
        #pragma unroll
        for (int ni = 0; ni < 4; ni++) {
            f1[ni] = *(const bf16x8*)&lB1[cur][(wn + ni * 16 + lm) * BK + lq * 8];
            f2[ni] = *(const bf16x8*)&lB2[cur][(wn + ni * 16 + lm) * BK + lq * 8];
        }
        #pragma unroll
        for (int mi = 0; mi < 4; mi++)
            #pragma unroll
            for (int ni = 0; ni < 4; ni++) {
                acc1[mi][ni] = __builtin_amdgcn_mfma_f32_16x16x32_bf16(af[mi], f1[ni], acc1[mi][ni], 0, 0, 0);
                acc2[mi][ni] = __builtin_amdgcn_mfma_f32_16x16x32_bf16(af[mi], f2[ni], acc2[mi][ni], 0, 0, 0);
            }
        __syncthreads();   // vmcnt(0)+lgkmcnt(0)+barrier: next buf ready, cur free
        cur ^= 1;
    }

    // epilogue: C/D layout col=lane&15, row=(lane>>4)*4+r  [m89-verified]
    constexpr float subdt = 1.0f / (float)ODE_STEPS;
    const size_t wslot = (((size_t)bid * 4 + w) * 16) * 64 + l;

    float pc1[4], pc2[4];   // per-ni hoisted: scale (STEP) or biases (!STEP)
    #pragma unroll
    for (int ni = 0; ni < 4; ni++) {
        const int gn = n0 + wn + ni * 16 + lm;
        if (STEP) {
            pc1[ni] = subdt * __expf(-log_tau[gn]);
        } else {
            pc1[ni] = bias1[gn];
            pc2[ni] = bias2[gn];
        }
    }

    #pragma unroll
    for (int mi = 0; mi < 4; mi++) {
        #pragma unroll
        for (int ni = 0; ni < 4; ni++) {
            const int gmb = m0 + wm + mi * 16 + lq * 4;
            const int gn  = n0 + wn + ni * 16 + lm;
            const size_t slot = wslot + (size_t)(mi * 4 + ni) * 64;
            if (STEP) {
                const float sc = pc1[ni];
                u16x8 gi = *(const u16x8*)&GXID[slot * 8];
                f32x4 st;
                if (h_init) {
                    #pragma unroll
                    for (int r = 0; r < 4; r++)
                        st[r] = h_init[(size_t)(gmb + r) * HIDC + gn];
                } else {
                    st = *(const f32x4*)&h_nat[slot * 4];
                }
                f32x4 hn;
                #pragma unroll
                for (int r = 0; r < 4; r++) {
                    float gx = bf2f((unsigned short)gi[r])     + acc1[mi][ni][r];
                    float dr = bf2f((unsigned short)gi[4 + r]) + acc2[mi][ni][r];
                    float gt = fast_tanh(dr) / (1.0f + __expf(-gx));
                    hn[r] = fmaf(sc, gt - st[r], st[r]);
                }
                if (h_out) {
                    #pragma unroll
                    for (int r = 0; r < 4; r++) {
                        size_t idx = (size_t)(gmb + r) * HIDC + gn;
                        h_out[idx]  = hn[r];
                        h_out2[idx] = hn[r];
                    }
                } else {
                    *(f32x4*)&h_nat[slot * 4] = hn;
                    #pragma unroll
                    for (int r = 0; r < 4; r++)
                        hbf_out[(size_t)(gmb + r) * HIDC + gn] = f2bf(hn[r]);
                }
            } else {
                u16x8 o;
                #pragma unroll
                for (int r = 0; r < 4; r++) {
                    o[r]     = f2bf(acc1[mi][ni][r] + pc1[ni]);
                    o[4 + r] = f2bf(acc2[mi][ni][r] + pc2[ni]);
                }
                *(u16x8*)&GXID_out[slot * 8] = o;
            }
        }
    }
}

extern "C" void kernel_launch(void* const* d_in, const int* in_sizes, int n_in,
                              void* d_out, int out_size, void* d_ws, size_t ws_size,
                              hipStream_t stream)
{
    const float* x    = (const float*)d_in[0];
    const float* h    = (const float*)d_in[1];
    const float* ltau = (const float*)d_in[2];
    const float* winw = (const float*)d_in[3];
    const float* winb = (const float*)d_in[4];
    const float* wrec = (const float*)d_in[5];
    const float* wg   = (const float*)d_in[6];
    const float* wgb  = (const float*)d_in[7];

    char* ws = (char*)d_ws;
    unsigned short* x_bf    = (unsigned short*)ws; ws += XN * 2;
    unsigned short* h_bf0   = (unsigned short*)ws; ws += HN * 2;
    unsigned short* h_bf1   = (unsigned short*)ws; ws += HN * 2;
    unsigned short* win_bf  = (unsigned short*)ws; ws += WINN * 2;
    unsigned short* wrec_bf = (unsigned short*)ws; ws += WRECN * 2;
    unsigned short* wgx_bf  = (unsigned short*)ws; ws += WINN * 2;
    unsigned short* wgh_bf  = (unsigned short*)ws; ws += WRECN * 2;
    unsigned short* GXID    = (unsigned short*)ws; ws += HN * 2 * 2;  // 32 MB
    float*          h_nat   = (float*)ws;          ws += HN * 4;      // 32 MB

    float* hout  = (float*)d_out;
    float* hout2 = hout + (size_t)B_DIM * HIDC;

    convert_all<<<(int)(TOTQ / 256), 256, 0, stream>>>(
        x, h, winw, wrec, wg, x_bf, h_bf0, win_bf, wrec_bf, wgx_bf, wgh_bf);

    // pre-loop: GXID = pack(x@Wgx^T + wgb, x@Win^T + winb) in native layout
    ltc_gemm<false><<<GRID, 256, 0, stream>>>(
        x_bf, wgx_bf, win_bf,
        nullptr, nullptr, nullptr, nullptr, nullptr, nullptr, nullptr,
        wgb, winb, GXID);

    unsigned short* hbf[2] = {h_bf0, h_bf1};
    for (int s = 0; s < ODE_STEPS; s++) {
        const bool last = (s == ODE_STEPS - 1);
        ltc_gemm<true><<<GRID, 256, 0, stream>>>(
            hbf[s & 1], wgh_bf, wrec_bf,
            GXID,
            (s == 0) ? h : nullptr,
            h_nat, ltau,
            last ? hout : nullptr, last ? hout2 : nullptr,
            last ? nullptr : hbf[(s + 1) & 1],
            nullptr, nullptr, nullptr);
    }
}